// Round 7
// baseline (339.449 us; speedup 1.0000x reference)
//
#include <hip/hip_runtime.h>
#include <stdint.h>

typedef short short8 __attribute__((ext_vector_type(8)));
typedef float f32x4 __attribute__((ext_vector_type(4)));
typedef float f32x16 __attribute__((ext_vector_type(16)));
typedef unsigned int u32x2 __attribute__((ext_vector_type(2)));
typedef unsigned int u32x4 __attribute__((ext_vector_type(4)));

#define T_DIM 2048
#define D_DIM 512
#define BM 32      // Q rows per block (R7: halved -> 2 blocks/CU)
#define BN 64
#define SSTR 72    // P LDS row stride in bf16 elems (pad 64+8)
#define KSTR_F 520 // fallback kernel K/Q stride
#define SCALE_LOG2E 0.06376353712072678f  // 1/sqrt(512) * log2(e)
#define ELEMS_PER_ARR (8u * 2048u * 512u)  // 8388608
#define WS_NEEDED (2u * ELEMS_PER_ARR * 2u) // 32 MiB: bf16 K + bf16 S^T

// round-half-up fp32 -> bf16 bits
__device__ __forceinline__ uint32_t bfbits(float x) {
    return (__float_as_uint(x) + 0x8000u) >> 16;
}
__device__ __forceinline__ uint32_t pk2(float lo, float hi) {
    return bfbits(lo) | ((__float_as_uint(hi) + 0x8000u) & 0xFFFF0000u);
}

// async global->LDS, 16 B per lane; LDS dst = base + lane*16 (wave-uniform base)
__device__ __forceinline__ void dma16(const short* g, short* l) {
    __builtin_amdgcn_global_load_lds(
        (const __attribute__((address_space(1))) unsigned int*)g,
        (__attribute__((address_space(3))) unsigned int*)l, 16, 0, 0);
}

// ---------------- fused pre-pass --------------------------------------------
// blocks [0,4096): K fp32 -> bf16, per-row 16B-chunk XOR swizzle
//   ws row r (1KB, 64 chunks): ws chunk j = orig elems (j^(r&7))*8 .. +8
// blocks [4096,4608): S -> S^T bf16 tiled [b][kt][512][64], linear
//   (consumed straight from global into registers). Register-resident 8x8
//   transpose: no LDS, no barrier.
__global__ __launch_bounds__(256)
void prep(const float* __restrict__ kg, const float* __restrict__ sg,
          short* __restrict__ kws, short* __restrict__ sws) {
    int tid = threadIdx.x;
    if (blockIdx.x < 4096) {
        int gid = blockIdx.x * 256 + tid;            // one 16B out chunk each
        int row = gid >> 6;                          // 0..16383 (b*2048+key)
        int j   = gid & 63;
        const float* src = kg + (size_t)row * D_DIM + ((j ^ (row & 7)) << 3);
        f32x4 a = *(const f32x4*)src;
        f32x4 b = *(const f32x4*)(src + 4);
        u32x2 w0; w0[0] = pk2(a[0], a[1]); w0[1] = pk2(a[2], a[3]);
        u32x2 w1; w1[0] = pk2(b[0], b[1]); w1[1] = pk2(b[2], b[3]);
        short* dst = kws + (size_t)row * D_DIM + (j << 3);
        *(u32x2*)dst = w0;
        *(u32x2*)(dst + 4) = w1;
    } else {
        int bid = blockIdx.x - 4096;                 // 8 b x 32 kt x 2 dh
        int b  = bid >> 6;
        int kt = (bid >> 1) & 31;
        int dh = bid & 1;                            // d half: dh*256..+256
        int kc = tid & 7;                            // key 8-chunk within tile
        int dc = tid >> 3;                           // d 8-chunk within half
        const float* sb = sg + (size_t)b * T_DIM * D_DIM
                        + (size_t)(kt * 64 + kc * 8) * D_DIM + dh * 256 + dc * 8;
        f32x4 lo[8], hi[8];
#pragma unroll
        for (int i = 0; i < 8; ++i) {
            lo[i] = *(const f32x4*)(sb + (size_t)i * D_DIM);
            hi[i] = *(const f32x4*)(sb + (size_t)i * D_DIM + 4);
        }
        short* out = sws + (size_t)b * (512u * 2048u) + (size_t)kt * (512 * 64)
                   + (size_t)(dh * 256 + dc * 8) * 64;
#pragma unroll
        for (int u = 0; u < 8; ++u) {                // d = base + u
            float c[8];
#pragma unroll
            for (int j = 0; j < 8; ++j)
                c[j] = (u < 4) ? lo[j][u] : hi[j][u - 4];
            u32x4 w;
            w[0] = pk2(c[0], c[1]); w[1] = pk2(c[2], c[3]);
            w[2] = pk2(c[4], c[5]); w[3] = pk2(c[6], c[7]);
            *(u32x4*)(out + (size_t)u * 64 + (kc << 3)) = w;
        }
    }
}

// ---------------- main kernel: BM=32, 4 waves, 2 blocks/CU --------------------
// R6 post-mortem: single 512-thread block/CU left the LDS pipe ~50% idle at
// the barrier drains. R7: halve the block (32 Q rows, 4 waves, ~70KB LDS) and
// double the grid to 512 -> 2 independent blocks/CU whose barriers interleave.
// QK^T: wave (qs=wv>>1, kh=wv&1): rows qs*16..+16 (qf in regs, 64 VGPR),
//       keys kh*32..+32. PV: wave owns ALL 32 rows x d-cols wv*128..+128
//       (4 x 32x32 tiles) -> each af P-read feeds 4 MFMAs (af traffic halved);
//       S^T global->regs (sf, 64 VGPR transient), issued phase-1 top so QK^T
//       (~2.5k cy) hides L2 latency; barrier-1 vmcnt drain syncs it.
// Regs: qf 64 + accO 64 + sf 64 + temps ~ 220 < 256 -> no spill expected.
__global__ __launch_bounds__(256, 2)
void saa_main(const float* __restrict__ qg, const short* __restrict__ kws,
              const float* __restrict__ vg, const short* __restrict__ sws,
              float* __restrict__ og)
{
    __shared__ __align__(16) short Kl[64 * 512];    // K tile, chunk-swizzled
    __shared__ __align__(16) short Pl[32 * SSTR];   // P tile, padded
    __shared__ float lpart[2][32];

    const int tid  = threadIdx.x;
    const int wv   = tid >> 6;        // 0..3
    const int lane = tid & 63;
    const int c    = lane & 15;
    const int quad = lane >> 4;
    const int qs   = wv >> 1;         // QK^T: 16-row stripe (0..1)
    const int kh   = wv & 1;          // QK^T: 32-key half
    const int m32  = lane & 31;       // PV: m/n lane index
    const int h32  = lane >> 5;       // PV: k-half selector
    const int b    = blockIdx.x & 7;  // batch -> XCD affinity
    const int qbase = (blockIdx.x >> 3) * BM;
    const int sw   = c & 7;           // QK^T read-side XOR swizzle key

    const float* qb = qg + (size_t)b * T_DIM * D_DIM;
    const float* vb = vg + (size_t)b * T_DIM * D_DIM;
    float*       ob = og + (size_t)b * T_DIM * D_DIM;
    const short* kwb = kws + (size_t)b * T_DIM * D_DIM;
    const short* swb = sws + (size_t)b * (512u * 2048u);

    // ---- Q -> registers directly (fp32 global, read once) ----
    short8 qf[16];
    {
        const float* qr = qb + (size_t)(qbase + qs * 16 + c) * D_DIM + quad * 8;
#pragma unroll
        for (int dc = 0; dc < 16; ++dc) {
            f32x4 a  = *(const f32x4*)(qr + dc * 32);
            f32x4 b4 = *(const f32x4*)(qr + dc * 32 + 4);
            u32x4 w;
            w[0] = pk2(a[0], a[1]);  w[1] = pk2(a[2], a[3]);
            w[2] = pk2(b4[0], b4[1]); w[3] = pk2(b4[2], b4[3]);
            qf[dc] = *(short8*)&w;
        }
    }

    // ---- preload K(0); barrier drains it ----
#pragma unroll
    for (int j = 0; j < 16; ++j) {
        int r = wv * 16 + j;
        dma16(kwb + r * 512 + lane * 8, &Kl[r * 512]);
    }
    __syncthreads();

    f32x16 accO[4];                    // 4 x (32x32) d-tiles
#pragma unroll
    for (int t = 0; t < 4; ++t) accO[t] = 0.0f;
    float rs[4] = {0.f, 0.f, 0.f, 0.f};

    // per-lane S^T base: d-row = wv*128 + m32, key-chunk h32
    const short* sbase = swb + (size_t)(wv * 128 + m32) * 64 + h32 * 8;
    const int krow0 = kh * 32 + c;
    const int krow1 = kh * 32 + 16 + c;

#pragma unroll 1
    for (int kc = 0; kc < T_DIM; kc += BN) {
        // ===== phase 1: issue sf loads, QK^T, exp, P write ==================
        short8 sf[4][4];               // [t][kb] -- 64 VGPR, lands under QK^T
        {
            const short* st = sbase + (size_t)(kc >> 6) * (512 * 64);
#pragma unroll
            for (int t = 0; t < 4; ++t)
#pragma unroll
                for (int kb = 0; kb < 4; ++kb)
                    sf[t][kb] = *(const short8*)(st + t * (32 * 64) + kb * 16);
        }
        {
            f32x4 acc0 = 0.0f, acc1 = 0.0f;
#pragma unroll
            for (int dc = 0; dc < 16; ++dc) {
                int cb = ((dc * 4 + quad) ^ sw) << 4;
                short8 kf0 = *(const short8*)((const char*)Kl + krow0 * 1024 + cb);
                short8 kf1 = *(const short8*)((const char*)Kl + krow1 * 1024 + cb);
                acc0 = __builtin_amdgcn_mfma_f32_16x16x32_bf16(qf[dc], kf0, acc0, 0, 0, 0);
                acc1 = __builtin_amdgcn_mfma_f32_16x16x32_bf16(qf[dc], kf1, acc1, 0, 0, 0);
            }
#pragma unroll
            for (int r = 0; r < 4; ++r) {
                float p0 = exp2f(acc0[r] * SCALE_LOG2E);
                float p1 = exp2f(acc1[r] * SCALE_LOG2E);
                rs[r] += p0 + p1;
                Pl[(qs * 16 + quad * 4 + r) * SSTR + kh * 32 + c] = (short)bfbits(p0);
                Pl[(qs * 16 + quad * 4 + r) * SSTR + kh * 32 + 16 + c] = (short)bfbits(p1);
            }
        }
        __syncthreads();   // P ready; sf drained; Kl reads done

        // ===== phase 2: issue K(i+1) DMA, then PV from Pl + sf ==============
        if (kc + BN < T_DIM) {
            const short* kt = kwb + (size_t)(kc + BN) * D_DIM;
#pragma unroll
            for (int j = 0; j < 16; ++j) {
                int r = wv * 16 + j;
                dma16(kt + r * 512 + lane * 8, &Kl[r * 512]);
            }
        }
        {
#pragma unroll
            for (int kb = 0; kb < 4; ++kb) {          // 16 keys per MFMA
                short8 af = *(const short8*)&Pl[m32 * SSTR + kb * 16 + h32 * 8];
#pragma unroll
                for (int t = 0; t < 4; ++t)
                    accO[t] = __builtin_amdgcn_mfma_f32_32x32x16_bf16(af, sf[t][kb], accO[t], 0, 0, 0);
            }
        }
        __syncthreads();   // Pl free; K(i+1) ready
    }

    // ---- combine row sums across the 2 key halves ----
#pragma unroll
    for (int r = 0; r < 4; ++r) {
        float v = rs[r];
        v += __shfl_xor(v, 1, 16);
        v += __shfl_xor(v, 2, 16);
        v += __shfl_xor(v, 4, 16);
        v += __shfl_xor(v, 8, 16);
        if (c == 0) lpart[kh][qs * 16 + quad * 4 + r] = v;
    }
    __syncthreads();

    // ---- epilogue: out = (accO / l) * V ----
    // 32x32 C layout: col = lane&31, row = (reg&3) + 8*(reg>>2) + 4*(lane>>5)
#pragma unroll
    for (int reg = 0; reg < 16; ++reg) {
        int qr2 = (reg & 3) + 8 * (reg >> 2) + 4 * h32;   // 0..31
        float inv = 1.0f / (lpart[0][qr2] + lpart[1][qr2]);
        size_t rowbase = (size_t)(qbase + qr2) * D_DIM + wv * 128 + m32;
#pragma unroll
        for (int t = 0; t < 4; ++t) {
            size_t idx = rowbase + t * 32;
            ob[idx] = accO[t][reg] * inv * vb[idx];
        }
    }
}

// ---------------- fallback (round-3 kernel) if ws too small -------------------
__global__ __launch_bounds__(1024, 4)
void saa_fallback(const float* __restrict__ qg, const float* __restrict__ kg,
                  const float* __restrict__ vg, const float* __restrict__ sg,
                  float* __restrict__ og)
{
    __shared__ __align__(16) short Kl[64 * KSTR_F];
    __shared__ __align__(16) short STl[512 * SSTR];
    __shared__ __align__(16) short Pl[64 * SSTR];
    __shared__ float lpart[4][64];

    const int tid  = threadIdx.x;
    const int wv   = tid >> 6;
    const int lane = tid & 63;
    const int c    = lane & 15;
    const int quad = lane >> 4;
    const int qsub = wv >> 2;
    const int kq   = wv & 3;
    const int b    = blockIdx.x & 7;
    const int qbase = (blockIdx.x >> 3) * 64;

    const float* qb = qg + (size_t)b * T_DIM * D_DIM;
    const float* kb = kg + (size_t)b * T_DIM * D_DIM;
    const float* vb = vg + (size_t)b * T_DIM * D_DIM;
    const float* sb = sg + (size_t)b * T_DIM * D_DIM;
    float*       ob = og + (size_t)b * T_DIM * D_DIM;

#pragma unroll
    for (int i = 0; i < 8; ++i) {
        int f = tid + 1024 * i, row = f >> 7, d4 = (f & 127) << 2;
        f32x4 v4 = *(const f32x4*)(qb + (size_t)(qbase + row) * D_DIM + d4);
        u32x2 w; w[0] = pk2(v4[0], v4[1]); w[1] = pk2(v4[2], v4[3]);
        *(u32x2*)&Kl[row * KSTR_F + d4] = w;
    }
    __syncthreads();
    short8 qf[16];
#pragma unroll
    for (int dc = 0; dc < 16; ++dc)
        qf[dc] = *(const short8*)&Kl[(qsub * 16 + c) * KSTR_F + dc * 32 + quad * 8];
    __syncthreads();

    f32x4 accO[4][2];
#pragma unroll
    for (int mt = 0; mt < 4; ++mt)
#pragma unroll
        for (int nt = 0; nt < 2; ++nt) accO[mt][nt] = 0.0f;
    float rs[4] = {0.f, 0.f, 0.f, 0.f};

#pragma unroll 1
    for (int kc = 0; kc < T_DIM; kc += BN) {
#pragma unroll
        for (int i = 0; i < 8; ++i) {
            int f = tid + 1024 * i, row = f >> 7, d4 = (f & 127) << 2;
            f32x4 v4 = *(const f32x4*)(kb + (size_t)(kc + row) * D_DIM + d4);
            u32x2 w; w[0] = pk2(v4[0], v4[1]); w[1] = pk2(v4[2], v4[3]);
            *(u32x2*)&Kl[row * KSTR_F + d4] = w;
        }
        {
            int kp = tid & 31, dblk = tid >> 5;
            const float* s0 = sb + (size_t)(kc + 2 * kp) * D_DIM;
#pragma unroll
            for (int i = 0; i < 4; ++i) {
                int d = dblk * 16 + i * 4;
                f32x4 a = *(const f32x4*)(s0 + d);
                f32x4 b2 = *(const f32x4*)(s0 + D_DIM + d);
#pragma unroll
                for (int j = 0; j < 4; ++j)
                    *(uint32_t*)&STl[(d + j) * SSTR + 2 * kp] = pk2(a[j], b2[j]);
            }
        }
        __syncthreads();
        {
            f32x4 acc = 0.0f;
            const int krow = kq * 16 + c;
#pragma unroll
            for (int dc = 0; dc < 16; ++dc) {
                short8 kf = *(const short8*)&Kl[krow * KSTR_F + dc * 32 + quad * 8];
                acc = __builtin_amdgcn_mfma_f32_16x16x32_bf16(qf[dc], kf, acc, 0, 0, 0);
            }
#pragma unroll
            for (int r = 0; r < 4; ++r) {
                float p = exp2f(acc[r] * SCALE_LOG2E);
                rs[r] += p;
                Pl[(qsub * 16 + quad * 4 + r) * SSTR + kq * 16 + c] = (short)bfbits(p);
            }
        }
        __syncthreads();
#pragma unroll
        for (int ks = 0; ks < 2; ++ks) {
#pragma unroll
            for (int nt = 0; nt < 2; ++nt) {
                short8 bf = *(const short8*)&STl[(wv * 32 + nt * 16 + c) * SSTR + ks * 32 + quad * 8];
#pragma unroll
                for (int mt = 0; mt < 4; ++mt) {
                    short8 af = *(const short8*)&Pl[(mt * 16 + c) * SSTR + ks * 32 + quad * 8];
                    accO[mt][nt] = __builtin_amdgcn_mfma_f32_16x16x32_bf16(af, bf, accO[mt][nt], 0, 0, 0);
                }
            }
        }
        __syncthreads();
    }
#pragma unroll
    for (int r = 0; r < 4; ++r) {
        float v = rs[r];
        v += __shfl_xor(v, 1, 16);
        v += __shfl_xor(v, 2, 16);
        v += __shfl_xor(v, 4, 16);
        v += __shfl_xor(v, 8, 16);
        if (c == 0) lpart[kq][qsub * 16 + quad * 4 + r] = v;
    }
    __syncthreads();
#pragma unroll
    for (int mt = 0; mt < 4; ++mt) {
#pragma unroll
        for (int r = 0; r < 4; ++r) {
            int row = mt * 16 + quad * 4 + r;
            float inv = 1.0f / (lpart[0][row] + lpart[1][row] + lpart[2][row] + lpart[3][row]);
            size_t base = (size_t)(qbase + row) * D_DIM + wv * 32 + c;
#pragma unroll
            for (int nt = 0; nt < 2; ++nt) {
                size_t idx = base + nt * 16;
                ob[idx] = accO[mt][nt][r] * inv * vb[idx];
            }
        }
    }
}

extern "C" void kernel_launch(void* const* d_in, const int* in_sizes, int n_in,
                              void* d_out, int out_size, void* d_ws, size_t ws_size,
                              hipStream_t stream) {
    const float* q = (const float*)d_in[0];
    const float* k = (const float*)d_in[1];
    const float* v = (const float*)d_in[2];
    const float* s = (const float*)d_in[3];
    float* out = (float*)d_out;
    (void)in_sizes; (void)n_in; (void)out_size;

    if (ws_size >= (size_t)WS_NEEDED) {
        short* kws = (short*)d_ws;                 // 16 MiB bf16 K (swizzled rows)
        short* sws = kws + ELEMS_PER_ARR;          // 16 MiB bf16 S^T (tiled, linear)
        prep<<<dim3(4608), dim3(256), 0, stream>>>(k, s, kws, sws);
        saa_main<<<dim3(512), dim3(256), 0, stream>>>(q, kws, v, sws, out);
    } else {
        saa_fallback<<<dim3(256), dim3(1024), 0, stream>>>(q, k, v, s, out);
    }
}

// Round 8
// 249.342 us; speedup vs baseline: 1.3614x; 1.3614x over previous
//
#include <hip/hip_runtime.h>
#include <stdint.h>

typedef short short8 __attribute__((ext_vector_type(8)));
typedef float f32x4 __attribute__((ext_vector_type(4)));
typedef float f32x16 __attribute__((ext_vector_type(16)));
typedef unsigned int u32x2 __attribute__((ext_vector_type(2)));
typedef unsigned int u32x4 __attribute__((ext_vector_type(4)));

#define T_DIM 2048
#define D_DIM 512
#define BM 64
#define BN 64
#define SSTR 72    // P LDS row stride in bf16 elems (pad 64+8)
#define KSTR_F 520 // fallback kernel K/Q stride
#define SCALE_LOG2E 0.06376353712072678f  // 1/sqrt(512) * log2(e)
#define ELEMS_PER_ARR (8u * 2048u * 512u)  // 8388608
#define WS_NEEDED (2u * ELEMS_PER_ARR * 2u) // 32 MiB: bf16 K + bf16 S^T

// round-half-up fp32 -> bf16 bits
__device__ __forceinline__ uint32_t bfbits(float x) {
    return (__float_as_uint(x) + 0x8000u) >> 16;
}
__device__ __forceinline__ uint32_t pk2(float lo, float hi) {
    return bfbits(lo) | ((__float_as_uint(hi) + 0x8000u) & 0xFFFF0000u);
}

// async global->LDS, 16 B per lane; LDS dst = base + lane*16 (wave-uniform base)
__device__ __forceinline__ void dma16(const short* g, short* l) {
    __builtin_amdgcn_global_load_lds(
        (const __attribute__((address_space(1))) unsigned int*)g,
        (__attribute__((address_space(3))) unsigned int*)l, 16, 0, 0);
}

// ---------------- fused pre-pass (R8: throughput-restructured) ----------------
// blocks [0,512): K fp32 -> bf16, per-row 16B-chunk XOR swizzle.
//   8 grid-strided chunk-units per thread; all loads issued before stores
//   (8-deep memory parallelism per thread; old version had 1 load-pair in
//   flight across 4096 tiny blocks -> latency/launch bound).
//   ws row r (1KB, 64 chunks): ws chunk j = orig elems (j^(r&7))*8 .. +8
// blocks [512,1024): S -> S^T bf16 tiled [b][kt][512][64], chunk-swizzled
//   out tile d-row (128B, 8 chunks): ws chunk m = orig keys (m^(d&7))*8 .. +8
//   Register-resident 8x8 transpose: no LDS, no barrier.
__global__ __launch_bounds__(256)
void prep(const float* __restrict__ kg, const float* __restrict__ sg,
          short* __restrict__ kws, short* __restrict__ sws) {
    int tid = threadIdx.x;
    if (blockIdx.x < 512) {
        int gid0 = blockIdx.x * 256 + tid;           // + it*131072, 8 its
        f32x4 a[8], b[8];
#pragma unroll
        for (int it = 0; it < 8; ++it) {
            int gid = gid0 + it * (512 * 256);
            int row = gid >> 6;                      // 0..16383 (b*2048+key)
            int j   = gid & 63;
            const float* src = kg + (size_t)row * D_DIM + ((j ^ (row & 7)) << 3);
            a[it] = *(const f32x4*)src;
            b[it] = *(const f32x4*)(src + 4);
        }
#pragma unroll
        for (int it = 0; it < 8; ++it) {
            int gid = gid0 + it * (512 * 256);
            int row = gid >> 6;
            int j   = gid & 63;
            u32x4 w;
            w[0] = pk2(a[it][0], a[it][1]); w[1] = pk2(a[it][2], a[it][3]);
            w[2] = pk2(b[it][0], b[it][1]); w[3] = pk2(b[it][2], b[it][3]);
            *(u32x4*)(kws + (size_t)row * D_DIM + (j << 3)) = w;
        }
    } else {
        int bid = blockIdx.x - 512;                  // 8 b x 32 kt x 2 dh
        int b  = bid >> 6;
        int kt = (bid >> 1) & 31;
        int dh = bid & 1;                            // d half: dh*256..+256
        int kc = tid & 7;                            // key 8-chunk within tile
        int dc = tid >> 3;                           // d 8-chunk within half
        const float* sb = sg + (size_t)b * T_DIM * D_DIM
                        + (size_t)(kt * 64 + kc * 8) * D_DIM + dh * 256 + dc * 8;
        f32x4 lo[8], hi[8];
#pragma unroll
        for (int i = 0; i < 8; ++i) {
            lo[i] = *(const f32x4*)(sb + (size_t)i * D_DIM);
            hi[i] = *(const f32x4*)(sb + (size_t)i * D_DIM + 4);
        }
        short* out = sws + (size_t)b * (512u * 2048u) + (size_t)kt * (512 * 64)
                   + (size_t)(dh * 256 + dc * 8) * 64;
#pragma unroll
        for (int u = 0; u < 8; ++u) {                // d = base + u, d&7 == u
            float c[8];
#pragma unroll
            for (int j = 0; j < 8; ++j)
                c[j] = (u < 4) ? lo[j][u] : hi[j][u - 4];
            u32x4 w;
            w[0] = pk2(c[0], c[1]); w[1] = pk2(c[2], c[3]);
            w[2] = pk2(c[4], c[5]); w[3] = pk2(c[6], c[7]);
            *(u32x4*)(out + (size_t)u * 64 + ((kc ^ u) << 3)) = w;
        }
    }
}

// ---------------- main kernel: R2 structure (empirical best, 120us) -----------
// 8 waves, 2x register blocking.
// QK^T: wave (qh,kq) owns rows qh*32..+32 (Q in regs, 2 stripes) x keys kq*16..+16
// PV:   wave wv owns all 64 rows x cols wv*64..+64 (2x2 of 32x32 tiles)
//       S^T staged via DMA into STl (chunk-swizzled), read with XOR swizzle.
__global__ __launch_bounds__(512, 2)
void saa_main(const float* __restrict__ qg, const short* __restrict__ kws,
              const float* __restrict__ vg, const short* __restrict__ sws,
              float* __restrict__ og)
{
    __shared__ __align__(16) short Kl[64 * 512];    // K tile (and Q staging), swizzled
    __shared__ __align__(16) short STl[512 * 64];   // S^T tile, swizzled
    __shared__ __align__(16) short Pl[64 * SSTR];   // P tile, padded
    __shared__ float lpart[4][64];

    const int tid  = threadIdx.x;
    const int wv   = tid >> 6;
    const int lane = tid & 63;
    const int c    = lane & 15;
    const int quad = lane >> 4;
    const int qh   = wv >> 2;         // QK^T: 32-row half
    const int kq   = wv & 3;          // QK^T: 16-key quarter
    const int m32  = lane & 31;       // PV: m/n lane index
    const int h32  = lane >> 5;       // PV: k-half selector
    const int b    = blockIdx.x & 7;  // batch -> XCD affinity
    const int qbase = (blockIdx.x >> 3) * BM;
    const int sw   = c & 7;           // QK^T read-side XOR swizzle key

    const float* qb = qg + (size_t)b * T_DIM * D_DIM;
    const float* vb = vg + (size_t)b * T_DIM * D_DIM;
    float*       ob = og + (size_t)b * T_DIM * D_DIM;
    const short* kwb = kws + (size_t)b * T_DIM * D_DIM;
    const short* swb = sws + (size_t)b * (512u * 2048u);

    // ---- stage Q (fp32, read once) into Kl with the same chunk swizzle ----
#pragma unroll
    for (int i = 0; i < 16; ++i) {
        int f   = tid + 512 * i;
        int row = f >> 7;
        int d4  = (f & 127) << 2;
        f32x4 v4 = *(const f32x4*)(qb + (size_t)(qbase + row) * D_DIM + d4);
        u32x2 w; w[0] = pk2(v4[0], v4[1]); w[1] = pk2(v4[2], v4[3]);
        int byte = row * 1024 + ((((d4 >> 3) ^ (row & 7)) << 4) | ((d4 & 7) << 1));
        *(u32x2*)((char*)Kl + byte) = w;
    }
    __syncthreads();
    short8 qf[2][16];                  // 2 row-stripes x 16 d-chunks (128 VGPR)
#pragma unroll
    for (int s = 0; s < 2; ++s)
#pragma unroll
        for (int dc = 0; dc < 16; ++dc)
            qf[s][dc] = *(const short8*)((char*)Kl +
                            (qh * 32 + s * 16 + c) * 1024 +
                            (((dc * 4 + quad) ^ sw) << 4));
    __syncthreads();                   // Kl free for K(0) DMA

    // ---- preload K(0); barrier drains it ----
#pragma unroll
    for (int j = 0; j < 8; ++j) {
        int r = wv * 8 + j;
        dma16(kwb + r * 512 + lane * 8, &Kl[r * 512]);
    }
    __syncthreads();

    f32x16 accO[2][2];                 // [rh][t] 32x32 tiles (64 VGPR)
#pragma unroll
    for (int i = 0; i < 2; ++i)
#pragma unroll
        for (int j = 0; j < 2; ++j) accO[i][j] = 0.0f;
    float rs[2][4] = {{0.f, 0.f, 0.f, 0.f}, {0.f, 0.f, 0.f, 0.f}};

#pragma unroll 1
    for (int kc = 0; kc < T_DIM; kc += BN) {
        // ===== phase 1: issue S(i) DMA, then QK^T(i) + exp + P write =====
        {
            const short* st = swb + (size_t)(kc >> 6) * (512 * 64);
#pragma unroll
            for (int j = 0; j < 8; ++j) {
                int d0 = (wv * 8 + j) * 8;            // 8 S^T rows (1KB) per DMA
                dma16(st + d0 * 64 + lane * 8, &STl[d0 * 64]);
            }
        }
        {
            f32x4 acc0 = 0.0f, acc1 = 0.0f;
            const int krow = kq * 16 + c;
#pragma unroll
            for (int dc = 0; dc < 16; ++dc) {
                short8 kf = *(const short8*)((char*)Kl + krow * 1024 +
                                             (((dc * 4 + quad) ^ sw) << 4));
                acc0 = __builtin_amdgcn_mfma_f32_16x16x32_bf16(qf[0][dc], kf, acc0, 0, 0, 0);
                acc1 = __builtin_amdgcn_mfma_f32_16x16x32_bf16(qf[1][dc], kf, acc1, 0, 0, 0);
            }
#pragma unroll
            for (int r = 0; r < 4; ++r) {
                float p0 = exp2f(acc0[r] * SCALE_LOG2E);
                rs[0][r] += p0;
                Pl[(qh * 32 + quad * 4 + r) * SSTR + kq * 16 + c] = (short)bfbits(p0);
                float p1 = exp2f(acc1[r] * SCALE_LOG2E);
                rs[1][r] += p1;
                Pl[(qh * 32 + 16 + quad * 4 + r) * SSTR + kq * 16 + c] = (short)bfbits(p1);
            }
        }
        __syncthreads();   // P + S^T(i) ready; Kl free

        // ===== phase 2: issue K(i+1) DMA, then PV(i): 2x2 (32x32) per wave =====
        if (kc + BN < T_DIM) {
            const short* kt = kwb + (size_t)(kc + BN) * D_DIM;
#pragma unroll
            for (int j = 0; j < 8; ++j) {
                int r = wv * 8 + j;
                dma16(kt + r * 512 + lane * 8, &Kl[r * 512]);
            }
        }
        {
            const int dsw = m32 & 7;                  // (wv*64|t*32) % 8 == 0
#pragma unroll
            for (int kb = 0; kb < 4; ++kb) {          // 16 keys per MFMA
                short8 af0 = *(const short8*)&Pl[(m32) * SSTR + kb * 16 + h32 * 8];
                short8 af1 = *(const short8*)&Pl[(32 + m32) * SSTR + kb * 16 + h32 * 8];
#pragma unroll
                for (int t = 0; t < 2; ++t) {
                    const int dcol = wv * 64 + t * 32 + m32;
                    short8 bf = *(const short8*)((char*)STl + dcol * 128 +
                                                 (((kb * 2 + h32) ^ dsw) << 4));
                    accO[0][t] = __builtin_amdgcn_mfma_f32_32x32x16_bf16(af0, bf, accO[0][t], 0, 0, 0);
                    accO[1][t] = __builtin_amdgcn_mfma_f32_32x32x16_bf16(af1, bf, accO[1][t], 0, 0, 0);
                }
            }
        }
        __syncthreads();   // Pl/STl free; K(i+1) ready
    }

    // ---- combine row sums across the 4 key quarters ----
#pragma unroll
    for (int s = 0; s < 2; ++s)
#pragma unroll
    for (int r = 0; r < 4; ++r) {
        float v = rs[s][r];
        v += __shfl_xor(v, 1, 16);
        v += __shfl_xor(v, 2, 16);
        v += __shfl_xor(v, 4, 16);
        v += __shfl_xor(v, 8, 16);
        if (c == 0) lpart[kq][qh * 32 + s * 16 + quad * 4 + r] = v;
    }
    __syncthreads();

    // ---- epilogue: out = (accO / l) * V ----
    // 32x32 C layout: col = lane&31, row = (reg&3) + 8*(reg>>2) + 4*(lane>>5)
#pragma unroll
    for (int rh = 0; rh < 2; ++rh)
#pragma unroll
    for (int reg = 0; reg < 16; ++reg) {
        int qr = rh * 32 + (reg & 3) + 8 * (reg >> 2) + 4 * h32;
        float inv = 1.0f / (lpart[0][qr] + lpart[1][qr] + lpart[2][qr] + lpart[3][qr]);
        size_t rowbase = (size_t)(qbase + qr) * D_DIM + wv * 64 + m32;
#pragma unroll
        for (int t = 0; t < 2; ++t) {
            size_t idx = rowbase + t * 32;
            ob[idx] = accO[rh][t][reg] * inv * vb[idx];
        }
    }
}

// ---------------- fallback (round-3 kernel) if ws too small -------------------
__global__ __launch_bounds__(1024, 4)
void saa_fallback(const float* __restrict__ qg, const float* __restrict__ kg,
                  const float* __restrict__ vg, const float* __restrict__ sg,
                  float* __restrict__ og)
{
    __shared__ __align__(16) short Kl[64 * KSTR_F];
    __shared__ __align__(16) short STl[512 * SSTR];
    __shared__ __align__(16) short Pl[64 * SSTR];
    __shared__ float lpart[4][64];

    const int tid  = threadIdx.x;
    const int wv   = tid >> 6;
    const int lane = tid & 63;
    const int c    = lane & 15;
    const int quad = lane >> 4;
    const int qsub = wv >> 2;
    const int kq   = wv & 3;
    const int b    = blockIdx.x & 7;
    const int qbase = (blockIdx.x >> 3) * BM;

    const float* qb = qg + (size_t)b * T_DIM * D_DIM;
    const float* kb = kg + (size_t)b * T_DIM * D_DIM;
    const float* vb = vg + (size_t)b * T_DIM * D_DIM;
    const float* sb = sg + (size_t)b * T_DIM * D_DIM;
    float*       ob = og + (size_t)b * T_DIM * D_DIM;

#pragma unroll
    for (int i = 0; i < 8; ++i) {
        int f = tid + 1024 * i, row = f >> 7, d4 = (f & 127) << 2;
        f32x4 v4 = *(const f32x4*)(qb + (size_t)(qbase + row) * D_DIM + d4);
        u32x2 w; w[0] = pk2(v4[0], v4[1]); w[1] = pk2(v4[2], v4[3]);
        *(u32x2*)&Kl[row * KSTR_F + d4] = w;
    }
    __syncthreads();
    short8 qf[16];
#pragma unroll
    for (int dc = 0; dc < 16; ++dc)
        qf[dc] = *(const short8*)&Kl[(qsub * 16 + c) * KSTR_F + dc * 32 + quad * 8];
    __syncthreads();

    f32x4 accO[4][2];
#pragma unroll
    for (int mt = 0; mt < 4; ++mt)
#pragma unroll
        for (int nt = 0; nt < 2; ++nt) accO[mt][nt] = 0.0f;
    float rs[4] = {0.f, 0.f, 0.f, 0.f};

#pragma unroll 1
    for (int kc = 0; kc < T_DIM; kc += BN) {
#pragma unroll
        for (int i = 0; i < 8; ++i) {
            int f = tid + 1024 * i, row = f >> 7, d4 = (f & 127) << 2;
            f32x4 v4 = *(const f32x4*)(kb + (size_t)(kc + row) * D_DIM + d4);
            u32x2 w; w[0] = pk2(v4[0], v4[1]); w[1] = pk2(v4[2], v4[3]);
            *(u32x2*)&Kl[row * KSTR_F + d4] = w;
        }
        {
            int kp = tid & 31, dblk = tid >> 5;
            const float* s0 = sb + (size_t)(kc + 2 * kp) * D_DIM;
#pragma unroll
            for (int i = 0; i < 4; ++i) {
                int d = dblk * 16 + i * 4;
                f32x4 a = *(const f32x4*)(s0 + d);
                f32x4 b2 = *(const f32x4*)(s0 + D_DIM + d);
#pragma unroll
                for (int j = 0; j < 4; ++j)
                    *(uint32_t*)&STl[(d + j) * SSTR + 2 * kp] = pk2(a[j], b2[j]);
            }
        }
        __syncthreads();
        {
            f32x4 acc = 0.0f;
            const int krow = kq * 16 + c;
#pragma unroll
            for (int dc = 0; dc < 16; ++dc) {
                short8 kf = *(const short8*)&Kl[krow * KSTR_F + dc * 32 + quad * 8];
                acc = __builtin_amdgcn_mfma_f32_16x16x32_bf16(qf[dc], kf, acc, 0, 0, 0);
            }
#pragma unroll
            for (int r = 0; r < 4; ++r) {
                float p = exp2f(acc[r] * SCALE_LOG2E);
                rs[r] += p;
                Pl[(qsub * 16 + quad * 4 + r) * SSTR + kq * 16 + c] = (short)bfbits(p);
            }
        }
        __syncthreads();
#pragma unroll
        for (int ks = 0; ks < 2; ++ks) {
#pragma unroll
            for (int nt = 0; nt < 2; ++nt) {
                short8 bf = *(const short8*)&STl[(wv * 32 + nt * 16 + c) * SSTR + ks * 32 + quad * 8];
#pragma unroll
                for (int mt = 0; mt < 4; ++mt) {
                    short8 af = *(const short8*)&Pl[(mt * 16 + c) * SSTR + ks * 32 + quad * 8];
                    accO[mt][nt] = __builtin_amdgcn_mfma_f32_16x16x32_bf16(af, bf, accO[mt][nt], 0, 0, 0);
                }
            }
        }
        __syncthreads();
    }
#pragma unroll
    for (int r = 0; r < 4; ++r) {
        float v = rs[r];
        v += __shfl_xor(v, 1, 16);
        v += __shfl_xor(v, 2, 16);
        v += __shfl_xor(v, 4, 16);
        v += __shfl_xor(v, 8, 16);
        if (c == 0) lpart[kq][qsub * 16 + quad * 4 + r] = v;
    }
    __syncthreads();
#pragma unroll
    for (int mt = 0; mt < 4; ++mt) {
#pragma unroll
        for (int r = 0; r < 4; ++r) {
            int row = mt * 16 + quad * 4 + r;
            float inv = 1.0f / (lpart[0][row] + lpart[1][row] + lpart[2][row] + lpart[3][row]);
            size_t base = (size_t)(qbase + row) * D_DIM + wv * 32 + c;
#pragma unroll
            for (int nt = 0; nt < 2; ++nt) {
                size_t idx = base + nt * 16;
                ob[idx] = accO[mt][nt][r] * inv * vb[idx];
            }
        }
    }
}

extern "C" void kernel_launch(void* const* d_in, const int* in_sizes, int n_in,
                              void* d_out, int out_size, void* d_ws, size_t ws_size,
                              hipStream_t stream) {
    const float* q = (const float*)d_in[0];
    const float* k = (const float*)d_in[1];
    const float* v = (const float*)d_in[2];
    const float* s = (const float*)d_in[3];
    float* out = (float*)d_out;
    (void)in_sizes; (void)n_in; (void)out_size;

    if (ws_size >= (size_t)WS_NEEDED) {
        short* kws = (short*)d_ws;                 // 16 MiB bf16 K (swizzled rows)
        short* sws = kws + ELEMS_PER_ARR;          // 16 MiB bf16 S^T (tiled+swizzled)
        prep<<<dim3(1024), dim3(256), 0, stream>>>(k, s, kws, sws);
        saa_main<<<dim3(256), dim3(512), 0, stream>>>(q, kws, v, sws, out);
    } else {
        saa_fallback<<<dim3(256), dim3(1024), 0, stream>>>(q, k, v, s, out);
    }
}